// Round 1
// baseline (507.818 us; speedup 1.0000x reference)
//
#include <hip/hip_runtime.h>
#include <stdint.h>

typedef unsigned short u16;
typedef unsigned int u32;
typedef __attribute__((ext_vector_type(8))) __bf16 bf16x8;
typedef __attribute__((ext_vector_type(4))) float f32x4;

#define M_TOT 16384   // B*N tokens
#define DIMX  1024
#define NQKV  3072

// RNE float->bf16 (finite inputs only)
__device__ __forceinline__ u16 f2b(float f) {
  u32 u = __builtin_bit_cast(u32, f);
  u32 r = (u + 0x7fffu + ((u >> 16) & 1u)) >> 16;
  return (u16)r;
}

// async global->LDS, 16B per lane; lds dst must be wave-uniform base (lane*16 implicit)
__device__ __forceinline__ void gl2lds16(const void* g, void* l) {
  __builtin_amdgcn_global_load_lds((const __attribute__((address_space(1))) void*)g,
                                   (__attribute__((address_space(3))) void*)l,
                                   16, 0, 0);
}

// ---------------- RMSNorm: x (fp32, row 1024) -> xn (bf16) ----------------
__global__ __launch_bounds__(256) void k_rms(const float* __restrict__ x,
                                             const float* __restrict__ gamma,
                                             u16* __restrict__ xn) {
  int row = blockIdx.x;
  int t = threadIdx.x;
  const float4* xr = (const float4*)(x + (size_t)row * DIMX);
  float4 v = xr[t];
  float ss = v.x * v.x + v.y * v.y + v.z * v.z + v.w * v.w;
#pragma unroll
  for (int o = 32; o > 0; o >>= 1) ss += __shfl_xor(ss, o, 64);
  __shared__ float wss[4];
  int w = t >> 6;
  if ((t & 63) == 0) wss[w] = ss;
  __syncthreads();
  float tot = wss[0] + wss[1] + wss[2] + wss[3];
  float scale = 32.0f / fmaxf(sqrtf(tot), 1e-12f);  // sqrt(1024)=32
  float4 g = ((const float4*)gamma)[t];
  ushort4 o4;
  o4.x = f2b(v.x * scale * g.x);
  o4.y = f2b(v.y * scale * g.y);
  o4.z = f2b(v.z * scale * g.z);
  o4.w = f2b(v.w * scale * g.w);
  ((ushort4*)xn)[(size_t)row * 256 + t] = o4;
}

// ---------------- transpose-cast: in (R x C fp32) -> out (C x R bf16) ----------------
__global__ __launch_bounds__(256) void k_castT(const float* __restrict__ in,
                                               u16* __restrict__ out, int Rr, int Cc) {
  __shared__ float tile[32][33];
  int c0 = blockIdx.x * 32, r0 = blockIdx.y * 32;
  int tx = threadIdx.x, ty = threadIdx.y;  // 32 x 8
#pragma unroll
  for (int i = 0; i < 4; i++)
    tile[ty + i * 8][tx] = in[(size_t)(r0 + ty + i * 8) * Cc + c0 + tx];
  __syncthreads();
#pragma unroll
  for (int i = 0; i < 4; i++)
    out[(size_t)(c0 + ty + i * 8) * Rr + r0 + tx] = f2b(tile[tx][ty + i * 8]);
}

// ---------------- GEMM1: qkv = xn @ wqT^T; q,k stored transposed + col sumsq; v natural --------
__global__ __launch_bounds__(256) void k_gemm1(const u16* __restrict__ A,   // 16384x1024
                                               const u16* __restrict__ Bt,  // 3072x1024
                                               u16* __restrict__ qkT,       // 2048x16384
                                               u16* __restrict__ vmat,      // 16384x1024
                                               float* __restrict__ sumsq) { // [4][2048]
  __shared__ u16 Al[128 * 32];
  __shared__ u16 Bl[128 * 32];
  int m0 = blockIdx.x * 128;
  int n0 = blockIdx.y * 128;
  int t = threadIdx.x;
  int lane = t & 63, w = t >> 6;
  int wi = w >> 1, wj = w & 1;
  int r16 = lane & 15, q = lane >> 4;
  f32x4 acc[4][4] = {};
  for (int k0 = 0; k0 < 1024; k0 += 32) {
    __syncthreads();
#pragma unroll
    for (int r = 0; r < 2; r++) {
      int chunk = (r << 8) + t;
      int row = chunk >> 2, cc = chunk & 3;
      u16* la = Al + ((r << 8) + (w << 6)) * 8;
      u16* lb = Bl + ((r << 8) + (w << 6)) * 8;
      gl2lds16(A + (size_t)(m0 + row) * 1024 + k0 + cc * 8, la);
      gl2lds16(Bt + (size_t)(n0 + row) * 1024 + k0 + cc * 8, lb);
    }
    __syncthreads();
    bf16x8 af[4], bfr[4];
#pragma unroll
    for (int i = 0; i < 4; i++) {
      af[i]  = *(const bf16x8*)(Al + (wi * 64 + i * 16 + r16) * 32 + q * 8);
      bfr[i] = *(const bf16x8*)(Bl + (wj * 64 + i * 16 + r16) * 32 + q * 8);
    }
#pragma unroll
    for (int i = 0; i < 4; i++)
#pragma unroll
      for (int j = 0; j < 4; j++)
        acc[i][j] = __builtin_amdgcn_mfma_f32_16x16x32_bf16(af[i], bfr[j], acc[i][j], 0, 0, 0);
  }
  int b = m0 >> 12;
  if (n0 < 2048) {
    // q/k tile: store transposed qkT[c][m], fuse column sum-of-squares
#pragma unroll
    for (int j = 0; j < 4; j++) {
      int c = n0 + wj * 64 + j * 16 + r16;
      float colss = 0.f;
#pragma unroll
      for (int i = 0; i < 4; i++) {
        f32x4 a = acc[i][j];
        colss += a.x * a.x + a.y * a.y + a.z * a.z + a.w * a.w;
        int m = m0 + wi * 64 + i * 16 + q * 4;
        ushort4 o4;
        o4.x = f2b(a.x); o4.y = f2b(a.y); o4.z = f2b(a.z); o4.w = f2b(a.w);
        *(ushort4*)(qkT + (size_t)c * M_TOT + m) = o4;
      }
      colss += __shfl_xor(colss, 16, 64);
      colss += __shfl_xor(colss, 32, 64);
      if (lane < 16) atomicAdd(&sumsq[b * 2048 + c], colss);
    }
  } else {
    // v tile: natural store
#pragma unroll
    for (int i = 0; i < 4; i++) {
      int m = m0 + wi * 64 + i * 16 + q * 4;
#pragma unroll
      for (int j = 0; j < 4; j++) {
        int c = (n0 - 2048) + wj * 64 + j * 16 + r16;
        f32x4 a = acc[i][j];
        vmat[(size_t)(m + 0) * 1024 + c] = f2b(a.x);
        vmat[(size_t)(m + 1) * 1024 + c] = f2b(a.y);
        vmat[(size_t)(m + 2) * 1024 + c] = f2b(a.z);
        vmat[(size_t)(m + 3) * 1024 + c] = f2b(a.w);
      }
    }
  }
}

// ---------------- S = Q^T K per (b,h), split-8 over n, atomic reduce ----------------
__global__ __launch_bounds__(256) void k_attn_s(const u16* __restrict__ qkT,
                                                float* __restrict__ S) {  // [64][64][64]
  int bh = blockIdx.x, split = blockIdx.y;
  int b = bh >> 4, h = bh & 15;
  int t = threadIdx.x, lane = t & 63, w = t >> 6;
  int r16 = lane & 15, q = lane >> 4;
  const u16* qbase = qkT + (size_t)(h * 64) * M_TOT + b * 4096;
  const u16* kbase = qkT + (size_t)(1024 + h * 64) * M_TOT + b * 4096;
  f32x4 acc[4][4] = {};
#pragma unroll
  for (int it = 0; it < 4; it++) {
    int n0 = split * 512 + it * 128 + w * 32;
    int kk = n0 + q * 8;
    bf16x8 af[4], bfr[4];
#pragma unroll
    for (int i = 0; i < 4; i++) af[i] = *(const bf16x8*)(qbase + (size_t)(i * 16 + r16) * M_TOT + kk);
#pragma unroll
    for (int j = 0; j < 4; j++) bfr[j] = *(const bf16x8*)(kbase + (size_t)(j * 16 + r16) * M_TOT + kk);
#pragma unroll
    for (int i = 0; i < 4; i++)
#pragma unroll
      for (int j = 0; j < 4; j++)
        acc[i][j] = __builtin_amdgcn_mfma_f32_16x16x32_bf16(af[i], bfr[j], acc[i][j], 0, 0, 0);
  }
  float* Sb = S + (size_t)bh * 4096;
#pragma unroll
  for (int i = 0; i < 4; i++) {
    int d0 = i * 16 + q * 4;
#pragma unroll
    for (int j = 0; j < 4; j++) {
      int e = j * 16 + r16;
      atomicAdd(&Sb[(d0 + 0) * 64 + e], acc[i][j].x);
      atomicAdd(&Sb[(d0 + 1) * 64 + e], acc[i][j].y);
      atomicAdd(&Sb[(d0 + 2) * 64 + e], acc[i][j].z);
      atomicAdd(&Sb[(d0 + 3) * 64 + e], acc[i][j].w);
    }
  }
}

// ---------------- scale + softmax -> PT[bh][e][d] bf16 ----------------
__global__ __launch_bounds__(64) void k_softmax(const float* __restrict__ S,
                                                const float* __restrict__ sumsq,
                                                const float* __restrict__ temp,
                                                u16* __restrict__ PT) {
  int bh = blockIdx.x;
  int b = bh >> 4, h = bh & 15;
  int d = threadIdx.x;
  __shared__ float rnk[64];
  rnk[d] = 1.0f / fmaxf(sqrtf(sumsq[b * 2048 + 1024 + h * 64 + d]), 1e-12f);
  __syncthreads();
  float nq = sqrtf(sumsq[b * 2048 + h * 64 + d]);
  float qs = 8.0f * __expf(temp[h]) / fmaxf(nq, 1e-12f);
  const float* Srow = S + ((size_t)bh * 64 + d) * 64;
  float vals[64];
  float mx = -3.0e38f;
#pragma unroll
  for (int e = 0; e < 64; e++) {
    float v = Srow[e] * qs * rnk[e];
    vals[e] = v;
    mx = fmaxf(mx, v);
  }
  float sum = 0.f;
#pragma unroll
  for (int e = 0; e < 64; e++) {
    float v = __expf(vals[e] - mx);
    vals[e] = v;
    sum += v;
  }
  float inv = 1.0f / sum;
#pragma unroll
  for (int e = 0; e < 64; e++)
    PT[((size_t)bh * 64 + e) * 64 + d] = f2b(vals[e] * inv);
}

// ---------------- MT_b[o][h*64+e] = sum_d woT[o][h*64+d] * PT[e][d] ----------------
__global__ __launch_bounds__(256) void k_m(const u16* __restrict__ woT,  // 1024x1024
                                           const u16* __restrict__ PT,   // [bh][64][64]
                                           u16* __restrict__ MT) {       // [4][1024][1024]
  int bh = blockIdx.x;
  int b = bh >> 4, h = bh & 15;
  int o0 = blockIdx.y * 128;
  int t = threadIdx.x, lane = t & 63, w = t >> 6;
  int r16 = lane & 15, q = lane >> 4;
  const u16* pbase = PT + (size_t)bh * 4096;
  f32x4 acc[2][4] = {};
#pragma unroll
  for (int ks = 0; ks < 2; ks++) {
    int kk = ks * 32 + q * 8;
    bf16x8 af[2], bfr[4];
#pragma unroll
    for (int i = 0; i < 2; i++)
      af[i] = *(const bf16x8*)(woT + (size_t)(o0 + w * 32 + i * 16 + r16) * 1024 + h * 64 + kk);
#pragma unroll
    for (int j = 0; j < 4; j++)
      bfr[j] = *(const bf16x8*)(pbase + (size_t)(j * 16 + r16) * 64 + kk);
#pragma unroll
    for (int i = 0; i < 2; i++)
#pragma unroll
      for (int j = 0; j < 4; j++)
        acc[i][j] = __builtin_amdgcn_mfma_f32_16x16x32_bf16(af[i], bfr[j], acc[i][j], 0, 0, 0);
  }
  u16* dst = MT + (size_t)b * 1024 * 1024;
#pragma unroll
  for (int i = 0; i < 2; i++) {
    int o = o0 + w * 32 + i * 16 + q * 4;
#pragma unroll
    for (int j = 0; j < 4; j++) {
      int e = h * 64 + j * 16 + r16;
      f32x4 a = acc[i][j];
      dst[(size_t)(o + 0) * 1024 + e] = f2b(a.x);
      dst[(size_t)(o + 1) * 1024 + e] = f2b(a.y);
      dst[(size_t)(o + 2) * 1024 + e] = f2b(a.z);
      dst[(size_t)(o + 3) * 1024 + e] = f2b(a.w);
    }
  }
}

// ---------------- GEMM2: out = vmat @ MT_b^T (fp32 out) ----------------
__global__ __launch_bounds__(256) void k_gemm2(const u16* __restrict__ A,   // 16384x1024
                                               const u16* __restrict__ Bt,  // [4][1024][1024]
                                               float* __restrict__ C) {     // 16384x1024 fp32
  __shared__ u16 Al[128 * 32];
  __shared__ u16 Bl[128 * 32];
  int m0 = blockIdx.x * 128;
  int n0 = blockIdx.y * 128;
  int b = m0 >> 12;
  const u16* Bb = Bt + (size_t)b * 1024 * 1024;
  int t = threadIdx.x;
  int lane = t & 63, w = t >> 6;
  int wi = w >> 1, wj = w & 1;
  int r16 = lane & 15, q = lane >> 4;
  f32x4 acc[4][4] = {};
  for (int k0 = 0; k0 < 1024; k0 += 32) {
    __syncthreads();
#pragma unroll
    for (int r = 0; r < 2; r++) {
      int chunk = (r << 8) + t;
      int row = chunk >> 2, cc = chunk & 3;
      u16* la = Al + ((r << 8) + (w << 6)) * 8;
      u16* lb = Bl + ((r << 8) + (w << 6)) * 8;
      gl2lds16(A + (size_t)(m0 + row) * 1024 + k0 + cc * 8, la);
      gl2lds16(Bb + (size_t)(n0 + row) * 1024 + k0 + cc * 8, lb);
    }
    __syncthreads();
    bf16x8 af[4], bfr[4];
#pragma unroll
    for (int i = 0; i < 4; i++) {
      af[i]  = *(const bf16x8*)(Al + (wi * 64 + i * 16 + r16) * 32 + q * 8);
      bfr[i] = *(const bf16x8*)(Bl + (wj * 64 + i * 16 + r16) * 32 + q * 8);
    }
#pragma unroll
    for (int i = 0; i < 4; i++)
#pragma unroll
      for (int j = 0; j < 4; j++)
        acc[i][j] = __builtin_amdgcn_mfma_f32_16x16x32_bf16(af[i], bfr[j], acc[i][j], 0, 0, 0);
  }
#pragma unroll
  for (int i = 0; i < 4; i++) {
    int m = m0 + wi * 64 + i * 16 + q * 4;
#pragma unroll
    for (int j = 0; j < 4; j++) {
      int c = n0 + wj * 64 + j * 16 + r16;
      f32x4 a = acc[i][j];
      C[(size_t)(m + 0) * 1024 + c] = a.x;
      C[(size_t)(m + 1) * 1024 + c] = a.y;
      C[(size_t)(m + 2) * 1024 + c] = a.z;
      C[(size_t)(m + 3) * 1024 + c] = a.w;
    }
  }
}

extern "C" void kernel_launch(void* const* d_in, const int* in_sizes, int n_in,
                              void* d_out, int out_size, void* d_ws, size_t ws_size,
                              hipStream_t stream) {
  const float* x     = (const float*)d_in[0];
  const float* gamma = (const float*)d_in[1];
  const float* wqkv  = (const float*)d_in[2];  // (1024, 3072)
  const float* temp  = (const float*)d_in[3];  // (16,1,1)
  const float* wout  = (const float*)d_in[4];  // (1024, 1024)
  float* out = (float*)d_out;

  char* ws = (char*)d_ws;
  size_t off = 0;
  u16* xn = (u16*)(ws + off);    off += (size_t)M_TOT * 1024 * 2;   // 32M
  u16* wqT = (u16*)(ws + off);   off += (size_t)3072 * 1024 * 2;    // 6M
  u16* woT = (u16*)(ws + off);   off += (size_t)1024 * 1024 * 2;    // 2M
  u16* qkT = (u16*)(ws + off);   off += (size_t)2048 * M_TOT * 2;   // 64M
  u16* vmat = (u16*)(ws + off);  off += (size_t)M_TOT * 1024 * 2;   // 32M
  float* sumsq = (float*)(ws + off); off += (size_t)4 * 2048 * 4;   // 32K
  float* S = (float*)(ws + off); off += (size_t)64 * 64 * 64 * 4;   // 1M
  u16* PT = (u16*)(ws + off);    off += (size_t)64 * 64 * 64 * 2;   // 0.5M
  u16* MT = (u16*)(ws + off);    off += (size_t)4 * 1024 * 1024 * 2;// 8M

  // zero the atomic-accumulated buffers (sumsq + S are contiguous)
  hipMemsetAsync((void*)sumsq, 0, (size_t)4 * 2048 * 4 + (size_t)64 * 64 * 64 * 4, stream);

  k_rms<<<16384, 256, 0, stream>>>(x, gamma, xn);
  dim3 cb(32, 8);
  k_castT<<<dim3(3072 / 32, 1024 / 32), cb, 0, stream>>>(wqkv, wqT, 1024, 3072);
  k_castT<<<dim3(1024 / 32, 1024 / 32), cb, 0, stream>>>(wout, woT, 1024, 1024);
  k_gemm1<<<dim3(128, 24), 256, 0, stream>>>(xn, wqT, qkT, vmat, sumsq);
  k_attn_s<<<dim3(64, 8), 256, 0, stream>>>(qkT, S);
  k_softmax<<<64, 64, 0, stream>>>(S, sumsq, temp, PT);
  k_m<<<dim3(64, 8), 256, 0, stream>>>(woT, PT, MT);
  k_gemm2<<<dim3(128, 8), 256, 0, stream>>>(vmat, MT, out);
}

// Round 2
// 384.385 us; speedup vs baseline: 1.3211x; 1.3211x over previous
//
#include <hip/hip_runtime.h>
#include <stdint.h>

typedef unsigned short u16;
typedef unsigned int u32;
typedef __attribute__((ext_vector_type(8))) __bf16 bf16x8;
typedef __attribute__((ext_vector_type(4))) float f32x4;

#define M_TOT 16384   // B*N tokens
#define DIMX  1024

// RNE float->bf16 (finite inputs only)
__device__ __forceinline__ u16 f2b(float f) {
  u32 u = __builtin_bit_cast(u32, f);
  u32 r = (u + 0x7fffu + ((u >> 16) & 1u)) >> 16;
  return (u16)r;
}

__device__ __forceinline__ void gl2lds16(const void* g, void* l) {
  __builtin_amdgcn_global_load_lds((const __attribute__((address_space(1))) void*)g,
                                   (__attribute__((address_space(3))) void*)l,
                                   16, 0, 0);
}

// ---------------- RMSNorm ----------------
__global__ __launch_bounds__(256) void k_rms(const float* __restrict__ x,
                                             const float* __restrict__ gamma,
                                             u16* __restrict__ xn) {
  int row = blockIdx.x;
  int t = threadIdx.x;
  const float4* xr = (const float4*)(x + (size_t)row * DIMX);
  float4 v = xr[t];
  float ss = v.x * v.x + v.y * v.y + v.z * v.z + v.w * v.w;
#pragma unroll
  for (int o = 32; o > 0; o >>= 1) ss += __shfl_xor(ss, o, 64);
  __shared__ float wss[4];
  int w = t >> 6;
  if ((t & 63) == 0) wss[w] = ss;
  __syncthreads();
  float tot = wss[0] + wss[1] + wss[2] + wss[3];
  float scale = 32.0f / fmaxf(sqrtf(tot), 1e-12f);
  float4 g = ((const float4*)gamma)[t];
  ushort4 o4;
  o4.x = f2b(v.x * scale * g.x);
  o4.y = f2b(v.y * scale * g.y);
  o4.z = f2b(v.z * scale * g.z);
  o4.w = f2b(v.w * scale * g.w);
  ((ushort4*)xn)[(size_t)row * 256 + t] = o4;
}

// ---------------- transpose-cast ----------------
__global__ __launch_bounds__(256) void k_castT(const float* __restrict__ in,
                                               u16* __restrict__ out, int Rr, int Cc) {
  __shared__ float tile[32][33];
  int c0 = blockIdx.x * 32, r0 = blockIdx.y * 32;
  int tx = threadIdx.x, ty = threadIdx.y;
#pragma unroll
  for (int i = 0; i < 4; i++)
    tile[ty + i * 8][tx] = in[(size_t)(r0 + ty + i * 8) * Cc + c0 + tx];
  __syncthreads();
#pragma unroll
  for (int i = 0; i < 4; i++)
    out[(size_t)(c0 + ty + i * 8) * Rr + r0 + tx] = f2b(tile[tx][ty + i * 8]);
}

// ---------------- shared 128x128 GEMM core, BK=64 (2x16KB stages / barrier-pair) -----
// Ag/Bg pre-offset to tile origin; K=1024 row-major bf16, row stride 1024.
// SWAP=false: acc[i][j] reg-dim = A rows (m). SWAP=true: reg-dim = B rows (n).
template<bool SWAP>
__device__ __forceinline__ void gemm_core128(const u16* __restrict__ Ag,
                                             const u16* __restrict__ Bg,
                                             u16* Al, u16* Bl,  // each [2*4096]
                                             int t, f32x4 (&acc)[4][4]) {
  int w = t >> 6, lane = t & 63;
  int r16 = lane & 15, q = lane >> 4;
  int wi = w >> 1, wj = w & 1;
  for (int k0 = 0; k0 < 1024; k0 += 64) {
    __syncthreads();
#pragma unroll
    for (int h = 0; h < 2; h++) {
#pragma unroll
      for (int r = 0; r < 2; r++) {
        int chunk = (r << 8) + t;
        int row = chunk >> 2, cc = chunk & 3;
        u16* la = Al + h * 4096 + ((r << 8) + (w << 6)) * 8;
        u16* lb = Bl + h * 4096 + ((r << 8) + (w << 6)) * 8;
        gl2lds16(Ag + (size_t)row * 1024 + k0 + h * 32 + cc * 8, la);
        gl2lds16(Bg + (size_t)row * 1024 + k0 + h * 32 + cc * 8, lb);
      }
    }
    __syncthreads();
#pragma unroll
    for (int h = 0; h < 2; h++) {
      bf16x8 af[4], bfr[4];
#pragma unroll
      for (int i = 0; i < 4; i++) {
        af[i]  = *(const bf16x8*)(Al + h * 4096 + (wi * 64 + i * 16 + r16) * 32 + q * 8);
        bfr[i] = *(const bf16x8*)(Bl + h * 4096 + (wj * 64 + i * 16 + r16) * 32 + q * 8);
      }
#pragma unroll
      for (int i = 0; i < 4; i++)
#pragma unroll
        for (int j = 0; j < 4; j++)
          acc[i][j] = SWAP
            ? __builtin_amdgcn_mfma_f32_16x16x32_bf16(bfr[j], af[i], acc[i][j], 0, 0, 0)
            : __builtin_amdgcn_mfma_f32_16x16x32_bf16(af[i], bfr[j], acc[i][j], 0, 0, 0);
    }
  }
}

// ---------------- GEMM1 q/k: qkT transposed store + fused column sumsq ----------------
// grid 2048 linear: xcd=l&7, idx=l>>3; m_blk=xcd*16+(idx&15); n_blk=idx>>4 (0..15)
__global__ __launch_bounds__(256) void k_gemm1qk(const u16* __restrict__ A,
                                                 const u16* __restrict__ Bt,
                                                 u16* __restrict__ qkT,
                                                 float* __restrict__ sumsq) {
  __shared__ u16 Al[2 * 4096];
  __shared__ u16 Bl[2 * 4096];
  int l = blockIdx.x;
  int xcd = l & 7, idx = l >> 3;
  int m0 = (xcd * 16 + (idx & 15)) * 128;
  int n0 = (idx >> 4) * 128;
  int t = threadIdx.x, lane = t & 63, w = t >> 6;
  int wi = w >> 1, wj = w & 1;
  int r16 = lane & 15, q = lane >> 4;
  f32x4 acc[4][4] = {};
  gemm_core128<false>(A + (size_t)m0 * 1024, Bt + (size_t)n0 * 1024, Al, Bl, t, acc);
  int b = m0 >> 12;
#pragma unroll
  for (int j = 0; j < 4; j++) {
    int c = n0 + wj * 64 + j * 16 + r16;
    float colss = 0.f;
#pragma unroll
    for (int i = 0; i < 4; i++) {
      f32x4 a = acc[i][j];
      colss += a.x * a.x + a.y * a.y + a.z * a.z + a.w * a.w;
      int m = m0 + wi * 64 + i * 16 + q * 4;
      ushort4 o4;
      o4.x = f2b(a.x); o4.y = f2b(a.y); o4.z = f2b(a.z); o4.w = f2b(a.w);
      *(ushort4*)(qkT + (size_t)c * M_TOT + m) = o4;
    }
    colss += __shfl_xor(colss, 16, 64);
    colss += __shfl_xor(colss, 32, 64);
    if (lane < 16) atomicAdd(&sumsq[b * 2048 + c], colss);
  }
}

// ---------------- GEMM1 v: swapped operands -> ushort4 stores along c ----------------
// grid 1024 linear: n_blk=idx>>4 (0..7)
__global__ __launch_bounds__(256) void k_gemm1v(const u16* __restrict__ A,
                                                const u16* __restrict__ BtV,
                                                u16* __restrict__ vmat) {
  __shared__ u16 Al[2 * 4096];
  __shared__ u16 Bl[2 * 4096];
  int l = blockIdx.x;
  int xcd = l & 7, idx = l >> 3;
  int m0 = (xcd * 16 + (idx & 15)) * 128;
  int vc0 = (idx >> 4) * 128;
  int t = threadIdx.x, lane = t & 63, w = t >> 6;
  int wi = w >> 1, wj = w & 1;
  int r16 = lane & 15, q = lane >> 4;
  f32x4 acc[4][4] = {};
  gemm_core128<true>(A + (size_t)m0 * 1024, BtV + (size_t)vc0 * 1024, Al, Bl, t, acc);
#pragma unroll
  for (int i = 0; i < 4; i++) {
    int m = m0 + wi * 64 + i * 16 + r16;
#pragma unroll
    for (int j = 0; j < 4; j++) {
      int c = vc0 + wj * 64 + j * 16 + q * 4;
      f32x4 a = acc[i][j];
      ushort4 o4;
      o4.x = f2b(a.x); o4.y = f2b(a.y); o4.z = f2b(a.z); o4.w = f2b(a.w);
      *(ushort4*)(vmat + (size_t)m * 1024 + c) = o4;
    }
  }
}

// ---------------- S = Q^T K per (b,h), split-8 over n, atomic reduce ----------------
__global__ __launch_bounds__(256) void k_attn_s(const u16* __restrict__ qkT,
                                                float* __restrict__ S) {
  int bh = blockIdx.x, split = blockIdx.y;
  int b = bh >> 4, h = bh & 15;
  int t = threadIdx.x, lane = t & 63, w = t >> 6;
  int r16 = lane & 15, q = lane >> 4;
  const u16* qbase = qkT + (size_t)(h * 64) * M_TOT + b * 4096;
  const u16* kbase = qkT + (size_t)(1024 + h * 64) * M_TOT + b * 4096;
  f32x4 acc[4][4] = {};
#pragma unroll
  for (int it = 0; it < 4; it++) {
    int n0 = split * 512 + it * 128 + w * 32;
    int kk = n0 + q * 8;
    bf16x8 af[4], bfr[4];
#pragma unroll
    for (int i = 0; i < 4; i++) af[i] = *(const bf16x8*)(qbase + (size_t)(i * 16 + r16) * M_TOT + kk);
#pragma unroll
    for (int j = 0; j < 4; j++) bfr[j] = *(const bf16x8*)(kbase + (size_t)(j * 16 + r16) * M_TOT + kk);
#pragma unroll
    for (int i = 0; i < 4; i++)
#pragma unroll
      for (int j = 0; j < 4; j++)
        acc[i][j] = __builtin_amdgcn_mfma_f32_16x16x32_bf16(af[i], bfr[j], acc[i][j], 0, 0, 0);
  }
  float* Sb = S + (size_t)bh * 4096;
#pragma unroll
  for (int i = 0; i < 4; i++) {
    int d0 = i * 16 + q * 4;
#pragma unroll
    for (int j = 0; j < 4; j++) {
      int e = j * 16 + r16;
      atomicAdd(&Sb[(d0 + 0) * 64 + e], acc[i][j].x);
      atomicAdd(&Sb[(d0 + 1) * 64 + e], acc[i][j].y);
      atomicAdd(&Sb[(d0 + 2) * 64 + e], acc[i][j].z);
      atomicAdd(&Sb[(d0 + 3) * 64 + e], acc[i][j].w);
    }
  }
}

// ---------------- scale + softmax -> PT[bh][e][d] bf16 ----------------
__global__ __launch_bounds__(64) void k_softmax(const float* __restrict__ S,
                                                const float* __restrict__ sumsq,
                                                const float* __restrict__ temp,
                                                u16* __restrict__ PT) {
  int bh = blockIdx.x;
  int b = bh >> 4, h = bh & 15;
  int d = threadIdx.x;
  __shared__ float rnk[64];
  rnk[d] = 1.0f / fmaxf(sqrtf(sumsq[b * 2048 + 1024 + h * 64 + d]), 1e-12f);
  __syncthreads();
  float nq = sqrtf(sumsq[b * 2048 + h * 64 + d]);
  float qs = 8.0f * __expf(temp[h]) / fmaxf(nq, 1e-12f);
  const float* Srow = S + ((size_t)bh * 64 + d) * 64;
  float vals[64];
  float mx = -3.0e38f;
#pragma unroll
  for (int e = 0; e < 64; e++) {
    float v = Srow[e] * qs * rnk[e];
    vals[e] = v;
    mx = fmaxf(mx, v);
  }
  float sum = 0.f;
#pragma unroll
  for (int e = 0; e < 64; e++) {
    float v = __expf(vals[e] - mx);
    vals[e] = v;
    sum += v;
  }
  float inv = 1.0f / sum;
#pragma unroll
  for (int e = 0; e < 64; e++)
    PT[((size_t)bh * 64 + e) * 64 + d] = f2b(vals[e] * inv);
}

// ---------------- MT_b[o][h*64+e] = sum_d woT[o][h*64+d] * PT[e][d] ----------------
__global__ __launch_bounds__(256) void k_m(const u16* __restrict__ woT,
                                           const u16* __restrict__ PT,
                                           u16* __restrict__ MT) {
  int bh = blockIdx.x;
  int b = bh >> 4, h = bh & 15;
  int o0 = blockIdx.y * 128;
  int t = threadIdx.x, lane = t & 63, w = t >> 6;
  int r16 = lane & 15, q = lane >> 4;
  const u16* pbase = PT + (size_t)bh * 4096;
  f32x4 acc[2][4] = {};
#pragma unroll
  for (int ks = 0; ks < 2; ks++) {
    int kk = ks * 32 + q * 8;
    bf16x8 af[2], bfr[4];
#pragma unroll
    for (int i = 0; i < 2; i++)
      af[i] = *(const bf16x8*)(woT + (size_t)(o0 + w * 32 + i * 16 + r16) * 1024 + h * 64 + kk);
#pragma unroll
    for (int j = 0; j < 4; j++)
      bfr[j] = *(const bf16x8*)(pbase + (size_t)(j * 16 + r16) * 64 + kk);
#pragma unroll
    for (int i = 0; i < 2; i++)
#pragma unroll
      for (int j = 0; j < 4; j++)
        acc[i][j] = __builtin_amdgcn_mfma_f32_16x16x32_bf16(af[i], bfr[j], acc[i][j], 0, 0, 0);
  }
  u16* dst = MT + (size_t)b * 1024 * 1024;
#pragma unroll
  for (int i = 0; i < 2; i++) {
    int o = o0 + w * 32 + i * 16 + q * 4;
#pragma unroll
    for (int j = 0; j < 4; j++) {
      int e = h * 64 + j * 16 + r16;
      f32x4 a = acc[i][j];
      dst[(size_t)(o + 0) * 1024 + e] = f2b(a.x);
      dst[(size_t)(o + 1) * 1024 + e] = f2b(a.y);
      dst[(size_t)(o + 2) * 1024 + e] = f2b(a.z);
      dst[(size_t)(o + 3) * 1024 + e] = f2b(a.w);
    }
  }
}

// ---------------- GEMM2: out = vmat @ MT_b^T (fp32 out), swapped -> float4 stores ----
// grid 1024 linear: n_blk=idx>>4 (0..7)
__global__ __launch_bounds__(256) void k_gemm2(const u16* __restrict__ A,
                                               const u16* __restrict__ Bt,
                                               float* __restrict__ C) {
  __shared__ u16 Al[2 * 4096];
  __shared__ u16 Bl[2 * 4096];
  int l = blockIdx.x;
  int xcd = l & 7, idx = l >> 3;
  int m0 = (xcd * 16 + (idx & 15)) * 128;
  int n0 = (idx >> 4) * 128;
  int b = m0 >> 12;
  const u16* Bb = Bt + (size_t)b * 1024 * 1024;
  int t = threadIdx.x, lane = t & 63, w = t >> 6;
  int wi = w >> 1, wj = w & 1;
  int r16 = lane & 15, q = lane >> 4;
  f32x4 acc[4][4] = {};
  gemm_core128<true>(A + (size_t)m0 * 1024, Bb + (size_t)n0 * 1024, Al, Bl, t, acc);
#pragma unroll
  for (int i = 0; i < 4; i++) {
    int m = m0 + wi * 64 + i * 16 + r16;
#pragma unroll
    for (int j = 0; j < 4; j++) {
      int c = n0 + wj * 64 + j * 16 + q * 4;
      *(f32x4*)(C + (size_t)m * 1024 + c) = acc[i][j];
    }
  }
}

extern "C" void kernel_launch(void* const* d_in, const int* in_sizes, int n_in,
                              void* d_out, int out_size, void* d_ws, size_t ws_size,
                              hipStream_t stream) {
  const float* x     = (const float*)d_in[0];
  const float* gamma = (const float*)d_in[1];
  const float* wqkv  = (const float*)d_in[2];
  const float* temp  = (const float*)d_in[3];
  const float* wout  = (const float*)d_in[4];
  float* out = (float*)d_out;

  char* ws = (char*)d_ws;
  size_t off = 0;
  u16* xn = (u16*)(ws + off);    off += (size_t)M_TOT * 1024 * 2;
  u16* wqT = (u16*)(ws + off);   off += (size_t)3072 * 1024 * 2;
  u16* woT = (u16*)(ws + off);   off += (size_t)1024 * 1024 * 2;
  u16* qkT = (u16*)(ws + off);   off += (size_t)2048 * M_TOT * 2;
  u16* vmat = (u16*)(ws + off);  off += (size_t)M_TOT * 1024 * 2;
  float* sumsq = (float*)(ws + off); off += (size_t)4 * 2048 * 4;
  float* S = (float*)(ws + off); off += (size_t)64 * 64 * 64 * 4;
  u16* PT = (u16*)(ws + off);    off += (size_t)64 * 64 * 64 * 2;
  u16* MT = (u16*)(ws + off);    off += (size_t)4 * 1024 * 1024 * 2;

  hipMemsetAsync((void*)sumsq, 0, (size_t)4 * 2048 * 4 + (size_t)64 * 64 * 64 * 4, stream);

  k_rms<<<16384, 256, 0, stream>>>(x, gamma, xn);
  dim3 cb(32, 8);
  k_castT<<<dim3(3072 / 32, 1024 / 32), cb, 0, stream>>>(wqkv, wqT, 1024, 3072);
  k_castT<<<dim3(1024 / 32, 1024 / 32), cb, 0, stream>>>(wout, woT, 1024, 1024);
  k_gemm1qk<<<2048, 256, 0, stream>>>(xn, wqT, qkT, sumsq);
  k_gemm1v<<<1024, 256, 0, stream>>>(xn, wqT + (size_t)2048 * 1024, vmat);
  k_attn_s<<<dim3(64, 8), 256, 0, stream>>>(qkT, S);
  k_softmax<<<64, 64, 0, stream>>>(S, sumsq, temp, PT);
  k_m<<<dim3(64, 8), 256, 0, stream>>>(woT, PT, MT);
  k_gemm2<<<1024, 256, 0, stream>>>(vmat, MT, out);
}

// Round 3
// 375.169 us; speedup vs baseline: 1.3536x; 1.0246x over previous
//
#include <hip/hip_runtime.h>
#include <stdint.h>

typedef unsigned short u16;
typedef unsigned int u32;
typedef __attribute__((ext_vector_type(8))) __bf16 bf16x8;
typedef __attribute__((ext_vector_type(4))) float f32x4;

#define M_TOT 16384   // B*N tokens
#define DIMX  1024

// RNE float->bf16 (finite inputs only)
__device__ __forceinline__ u16 f2b(float f) {
  u32 u = __builtin_bit_cast(u32, f);
  u32 r = (u + 0x7fffu + ((u >> 16) & 1u)) >> 16;
  return (u16)r;
}

__device__ __forceinline__ void gl2lds16(const void* g, void* l) {
  __builtin_amdgcn_global_load_lds((const __attribute__((address_space(1))) void*)g,
                                   (__attribute__((address_space(3))) void*)l,
                                   16, 0, 0);
}

// ---------------- RMSNorm ----------------
__global__ __launch_bounds__(256) void k_rms(const float* __restrict__ x,
                                             const float* __restrict__ gamma,
                                             u16* __restrict__ xn) {
  int row = blockIdx.x;
  int t = threadIdx.x;
  const float4* xr = (const float4*)(x + (size_t)row * DIMX);
  float4 v = xr[t];
  float ss = v.x * v.x + v.y * v.y + v.z * v.z + v.w * v.w;
#pragma unroll
  for (int o = 32; o > 0; o >>= 1) ss += __shfl_xor(ss, o, 64);
  __shared__ float wss[4];
  int w = t >> 6;
  if ((t & 63) == 0) wss[w] = ss;
  __syncthreads();
  float tot = wss[0] + wss[1] + wss[2] + wss[3];
  float scale = 32.0f / fmaxf(sqrtf(tot), 1e-12f);
  float4 g = ((const float4*)gamma)[t];
  ushort4 o4;
  o4.x = f2b(v.x * scale * g.x);
  o4.y = f2b(v.y * scale * g.y);
  o4.z = f2b(v.z * scale * g.z);
  o4.w = f2b(v.w * scale * g.w);
  ((ushort4*)xn)[(size_t)row * 256 + t] = o4;
}

// ---------------- transpose-cast ----------------
__global__ __launch_bounds__(256) void k_castT(const float* __restrict__ in,
                                               u16* __restrict__ out, int Rr, int Cc) {
  __shared__ float tile[32][33];
  int c0 = blockIdx.x * 32, r0 = blockIdx.y * 32;
  int tx = threadIdx.x, ty = threadIdx.y;
#pragma unroll
  for (int i = 0; i < 4; i++)
    tile[ty + i * 8][tx] = in[(size_t)(r0 + ty + i * 8) * Cc + c0 + tx];
  __syncthreads();
#pragma unroll
  for (int i = 0; i < 4; i++)
    out[(size_t)(c0 + ty + i * 8) * Rr + r0 + tx] = f2b(tile[tx][ty + i * 8]);
}

// ---------------- shared 128x128 GEMM core, BK=64, XOR bank-swizzled LDS -----
// LDS slot(row, c) = row*4 + (c ^ ((row>>1)&3)), 16B chunks. Staging permutes the
// global chunk per lane (same 64B segment, coalescing intact); reads invert it.
// SWAP=false: acc reg-dim = A rows (m). SWAP=true: reg-dim = B rows (n).
template<bool SWAP>
__device__ __forceinline__ void gemm_core128(const u16* __restrict__ Ag,
                                             const u16* __restrict__ Bg,
                                             u16* Al, u16* Bl,  // each [2*4096]
                                             int t, f32x4 (&acc)[4][4]) {
  int w = t >> 6, lane = t & 63;
  int r16 = lane & 15, q = lane >> 4;
  int wi = w >> 1, wj = w & 1;
  int swz = (r16 >> 1) & 3;
  int qs8 = ((q ^ swz) & 3) * 8;  // swizzled k-chunk byte/2 offset for frag reads
  for (int k0 = 0; k0 < 1024; k0 += 64) {
    __syncthreads();
#pragma unroll
    for (int h = 0; h < 2; h++) {
#pragma unroll
      for (int r = 0; r < 2; r++) {
        int chunk = (r << 8) + t;
        int row = chunk >> 2;
        int cc = (chunk & 3) ^ ((row >> 1) & 3);  // inverse swizzle on source
        u16* la = Al + h * 4096 + ((r << 8) + (w << 6)) * 8;
        u16* lb = Bl + h * 4096 + ((r << 8) + (w << 6)) * 8;
        gl2lds16(Ag + (size_t)row * 1024 + k0 + h * 32 + cc * 8, la);
        gl2lds16(Bg + (size_t)row * 1024 + k0 + h * 32 + cc * 8, lb);
      }
    }
    __syncthreads();
#pragma unroll
    for (int h = 0; h < 2; h++) {
      bf16x8 af[4], bfr[4];
#pragma unroll
      for (int i = 0; i < 4; i++) {
        af[i]  = *(const bf16x8*)(Al + h * 4096 + (wi * 64 + i * 16 + r16) * 32 + qs8);
        bfr[i] = *(const bf16x8*)(Bl + h * 4096 + (wj * 64 + i * 16 + r16) * 32 + qs8);
      }
#pragma unroll
      for (int i = 0; i < 4; i++)
#pragma unroll
        for (int j = 0; j < 4; j++)
          acc[i][j] = SWAP
            ? __builtin_amdgcn_mfma_f32_16x16x32_bf16(bfr[j], af[i], acc[i][j], 0, 0, 0)
            : __builtin_amdgcn_mfma_f32_16x16x32_bf16(af[i], bfr[j], acc[i][j], 0, 0, 0);
    }
  }
}

// ---------------- GEMM1 merged q/k/v ----------------
// grid 3072 linear: xcd=l&7, idx=l>>3 (0..383); m_blk=xcd*16+(idx&15); n_blk=idx>>4 (0..23)
__global__ __launch_bounds__(256) void k_gemm1(const u16* __restrict__ A,
                                               const u16* __restrict__ Bt,   // 3072x1024
                                               u16* __restrict__ qkT,        // 2048x16384
                                               u16* __restrict__ vmat,       // 16384x1024
                                               float* __restrict__ sumsq) {  // [4][2048]
  __shared__ u16 Al[2 * 4096];
  __shared__ u16 Bl[2 * 4096];
  int l = blockIdx.x;
  int xcd = l & 7, idx = l >> 3;
  int m0 = (xcd * 16 + (idx & 15)) * 128;
  int n0 = (idx >> 4) * 128;
  int t = threadIdx.x, lane = t & 63, w = t >> 6;
  int wi = w >> 1, wj = w & 1;
  int r16 = lane & 15, q = lane >> 4;
  f32x4 acc[4][4] = {};
  if (n0 < 2048) {
    gemm_core128<false>(A + (size_t)m0 * 1024, Bt + (size_t)n0 * 1024, Al, Bl, t, acc);
    int b = m0 >> 12;
#pragma unroll
    for (int j = 0; j < 4; j++) {
      int c = n0 + wj * 64 + j * 16 + r16;
      float colss = 0.f;
#pragma unroll
      for (int i = 0; i < 4; i++) {
        f32x4 a = acc[i][j];
        colss += a.x * a.x + a.y * a.y + a.z * a.z + a.w * a.w;
        int m = m0 + wi * 64 + i * 16 + q * 4;
        ushort4 o4;
        o4.x = f2b(a.x); o4.y = f2b(a.y); o4.z = f2b(a.z); o4.w = f2b(a.w);
        *(ushort4*)(qkT + (size_t)c * M_TOT + m) = o4;
      }
      colss += __shfl_xor(colss, 16, 64);
      colss += __shfl_xor(colss, 32, 64);
      if (lane < 16) atomicAdd(&sumsq[b * 2048 + c], colss);
    }
  } else {
    gemm_core128<true>(A + (size_t)m0 * 1024, Bt + (size_t)n0 * 1024, Al, Bl, t, acc);
    int vc0 = n0 - 2048;
#pragma unroll
    for (int i = 0; i < 4; i++) {
      int m = m0 + wi * 64 + i * 16 + r16;
#pragma unroll
      for (int j = 0; j < 4; j++) {
        int c = vc0 + wj * 64 + j * 16 + q * 4;
        f32x4 a = acc[i][j];
        ushort4 o4;
        o4.x = f2b(a.x); o4.y = f2b(a.y); o4.z = f2b(a.z); o4.w = f2b(a.w);
        *(ushort4*)(vmat + (size_t)m * 1024 + c) = o4;
      }
    }
  }
}

// ---------------- S = Q^T K per (b,h), split-8 over n, atomic reduce ----------------
__global__ __launch_bounds__(256) void k_attn_s(const u16* __restrict__ qkT,
                                                float* __restrict__ S) {
  int bh = blockIdx.x, split = blockIdx.y;
  int b = bh >> 4, h = bh & 15;
  int t = threadIdx.x, lane = t & 63, w = t >> 6;
  int r16 = lane & 15, q = lane >> 4;
  const u16* qbase = qkT + (size_t)(h * 64) * M_TOT + b * 4096;
  const u16* kbase = qkT + (size_t)(1024 + h * 64) * M_TOT + b * 4096;
  f32x4 acc[4][4] = {};
#pragma unroll
  for (int it = 0; it < 4; it++) {
    int n0 = split * 512 + it * 128 + w * 32;
    int kk = n0 + q * 8;
    bf16x8 af[4], bfr[4];
#pragma unroll
    for (int i = 0; i < 4; i++) af[i] = *(const bf16x8*)(qbase + (size_t)(i * 16 + r16) * M_TOT + kk);
#pragma unroll
    for (int j = 0; j < 4; j++) bfr[j] = *(const bf16x8*)(kbase + (size_t)(j * 16 + r16) * M_TOT + kk);
#pragma unroll
    for (int i = 0; i < 4; i++)
#pragma unroll
      for (int j = 0; j < 4; j++)
        acc[i][j] = __builtin_amdgcn_mfma_f32_16x16x32_bf16(af[i], bfr[j], acc[i][j], 0, 0, 0);
  }
  float* Sb = S + (size_t)bh * 4096;
#pragma unroll
  for (int i = 0; i < 4; i++) {
    int d0 = i * 16 + q * 4;
#pragma unroll
    for (int j = 0; j < 4; j++) {
      int e = j * 16 + r16;
      atomicAdd(&Sb[(d0 + 0) * 64 + e], acc[i][j].x);
      atomicAdd(&Sb[(d0 + 1) * 64 + e], acc[i][j].y);
      atomicAdd(&Sb[(d0 + 2) * 64 + e], acc[i][j].z);
      atomicAdd(&Sb[(d0 + 3) * 64 + e], acc[i][j].w);
    }
  }
}

// ---------------- scale + softmax -> PT[bh][e][d] bf16 ----------------
__global__ __launch_bounds__(64) void k_softmax(const float* __restrict__ S,
                                                const float* __restrict__ sumsq,
                                                const float* __restrict__ temp,
                                                u16* __restrict__ PT) {
  int bh = blockIdx.x;
  int b = bh >> 4, h = bh & 15;
  int d = threadIdx.x;
  __shared__ float rnk[64];
  rnk[d] = 1.0f / fmaxf(sqrtf(sumsq[b * 2048 + 1024 + h * 64 + d]), 1e-12f);
  __syncthreads();
  float nq = sqrtf(sumsq[b * 2048 + h * 64 + d]);
  float qs = 8.0f * __expf(temp[h]) / fmaxf(nq, 1e-12f);
  const float* Srow = S + ((size_t)bh * 64 + d) * 64;
  float vals[64];
  float mx = -3.0e38f;
#pragma unroll
  for (int e = 0; e < 64; e++) {
    float v = Srow[e] * qs * rnk[e];
    vals[e] = v;
    mx = fmaxf(mx, v);
  }
  float sum = 0.f;
#pragma unroll
  for (int e = 0; e < 64; e++) {
    float v = __expf(vals[e] - mx);
    vals[e] = v;
    sum += v;
  }
  float inv = 1.0f / sum;
#pragma unroll
  for (int e = 0; e < 64; e++)
    PT[((size_t)bh * 64 + e) * 64 + d] = f2b(vals[e] * inv);
}

// ---------------- MT_b[o][h*64+e] = sum_d woT[o][h*64+d] * PT[e][d] ----------------
__global__ __launch_bounds__(256) void k_m(const u16* __restrict__ woT,
                                           const u16* __restrict__ PT,
                                           u16* __restrict__ MT) {
  int bh = blockIdx.x;
  int b = bh >> 4, h = bh & 15;
  int o0 = blockIdx.y * 128;
  int t = threadIdx.x, lane = t & 63, w = t >> 6;
  int r16 = lane & 15, q = lane >> 4;
  const u16* pbase = PT + (size_t)bh * 4096;
  f32x4 acc[2][4] = {};
#pragma unroll
  for (int ks = 0; ks < 2; ks++) {
    int kk = ks * 32 + q * 8;
    bf16x8 af[2], bfr[4];
#pragma unroll
    for (int i = 0; i < 2; i++)
      af[i] = *(const bf16x8*)(woT + (size_t)(o0 + w * 32 + i * 16 + r16) * 1024 + h * 64 + kk);
#pragma unroll
    for (int j = 0; j < 4; j++)
      bfr[j] = *(const bf16x8*)(pbase + (size_t)(j * 16 + r16) * 64 + kk);
#pragma unroll
    for (int i = 0; i < 2; i++)
#pragma unroll
      for (int j = 0; j < 4; j++)
        acc[i][j] = __builtin_amdgcn_mfma_f32_16x16x32_bf16(af[i], bfr[j], acc[i][j], 0, 0, 0);
  }
  u16* dst = MT + (size_t)b * 1024 * 1024;
#pragma unroll
  for (int i = 0; i < 2; i++) {
    int o = o0 + w * 32 + i * 16 + q * 4;
#pragma unroll
    for (int j = 0; j < 4; j++) {
      int e = h * 64 + j * 16 + r16;
      f32x4 a = acc[i][j];
      dst[(size_t)(o + 0) * 1024 + e] = f2b(a.x);
      dst[(size_t)(o + 1) * 1024 + e] = f2b(a.y);
      dst[(size_t)(o + 2) * 1024 + e] = f2b(a.z);
      dst[(size_t)(o + 3) * 1024 + e] = f2b(a.w);
    }
  }
}

// ---------------- GEMM2: out = vmat @ MT_b^T (fp32 out), swapped -> float4 stores ----
__global__ __launch_bounds__(256) void k_gemm2(const u16* __restrict__ A,
                                               const u16* __restrict__ Bt,
                                               float* __restrict__ C) {
  __shared__ u16 Al[2 * 4096];
  __shared__ u16 Bl[2 * 4096];
  int l = blockIdx.x;
  int xcd = l & 7, idx = l >> 3;
  int m0 = (xcd * 16 + (idx & 15)) * 128;
  int n0 = (idx >> 4) * 128;
  int b = m0 >> 12;
  const u16* Bb = Bt + (size_t)b * 1024 * 1024;
  int t = threadIdx.x, lane = t & 63, w = t >> 6;
  int wi = w >> 1, wj = w & 1;
  int r16 = lane & 15, q = lane >> 4;
  f32x4 acc[4][4] = {};
  gemm_core128<true>(A + (size_t)m0 * 1024, Bb + (size_t)n0 * 1024, Al, Bl, t, acc);
#pragma unroll
  for (int i = 0; i < 4; i++) {
    int m = m0 + wi * 64 + i * 16 + r16;
#pragma unroll
    for (int j = 0; j < 4; j++) {
      int c = n0 + wj * 64 + j * 16 + q * 4;
      *(f32x4*)(C + (size_t)m * 1024 + c) = acc[i][j];
    }
  }
}

extern "C" void kernel_launch(void* const* d_in, const int* in_sizes, int n_in,
                              void* d_out, int out_size, void* d_ws, size_t ws_size,
                              hipStream_t stream) {
  const float* x     = (const float*)d_in[0];
  const float* gamma = (const float*)d_in[1];
  const float* wqkv  = (const float*)d_in[2];
  const float* temp  = (const float*)d_in[3];
  const float* wout  = (const float*)d_in[4];
  float* out = (float*)d_out;

  char* ws = (char*)d_ws;
  size_t off = 0;
  u16* xn = (u16*)(ws + off);    off += (size_t)M_TOT * 1024 * 2;
  u16* wqT = (u16*)(ws + off);   off += (size_t)3072 * 1024 * 2;
  u16* woT = (u16*)(ws + off);   off += (size_t)1024 * 1024 * 2;
  u16* qkT = (u16*)(ws + off);   off += (size_t)2048 * M_TOT * 2;
  u16* vmat = (u16*)(ws + off);  off += (size_t)M_TOT * 1024 * 2;
  float* sumsq = (float*)(ws + off); off += (size_t)4 * 2048 * 4;
  float* S = (float*)(ws + off); off += (size_t)64 * 64 * 64 * 4;
  u16* PT = (u16*)(ws + off);    off += (size_t)64 * 64 * 64 * 2;
  u16* MT = (u16*)(ws + off);    off += (size_t)4 * 1024 * 1024 * 2;

  hipMemsetAsync((void*)sumsq, 0, (size_t)4 * 2048 * 4 + (size_t)64 * 64 * 64 * 4, stream);

  k_rms<<<16384, 256, 0, stream>>>(x, gamma, xn);
  dim3 cb(32, 8);
  k_castT<<<dim3(3072 / 32, 1024 / 32), cb, 0, stream>>>(wqkv, wqT, 1024, 3072);
  k_castT<<<dim3(1024 / 32, 1024 / 32), cb, 0, stream>>>(wout, woT, 1024, 1024);
  k_gemm1<<<3072, 256, 0, stream>>>(xn, wqT, qkT, vmat, sumsq);
  k_attn_s<<<dim3(64, 8), 256, 0, stream>>>(qkT, S);
  k_softmax<<<64, 64, 0, stream>>>(S, sumsq, temp, PT);
  k_m<<<dim3(64, 8), 256, 0, stream>>>(woT, PT, MT);
  k_gemm2<<<1024, 256, 0, stream>>>(vmat, MT, out);
}

// Round 5
// 367.248 us; speedup vs baseline: 1.3828x; 1.0216x over previous
//
#include <hip/hip_runtime.h>
#include <stdint.h>

typedef unsigned short u16;
typedef unsigned int u32;
typedef __attribute__((ext_vector_type(8))) __bf16 bf16x8;
typedef __attribute__((ext_vector_type(4))) float f32x4;

#define M_TOT 16384   // B*N tokens
#define DIMX  1024

// RNE float->bf16 (finite inputs only)
__device__ __forceinline__ u16 f2b(float f) {
  u32 u = __builtin_bit_cast(u32, f);
  u32 r = (u + 0x7fffu + ((u >> 16) & 1u)) >> 16;
  return (u16)r;
}

__device__ __forceinline__ void gl2lds16(const void* g, void* l) {
  __builtin_amdgcn_global_load_lds((const __attribute__((address_space(1))) void*)g,
                                   (__attribute__((address_space(3))) void*)l,
                                   16, 0, 0);
}

// ---------------- RMSNorm ----------------
__global__ __launch_bounds__(256) void k_rms(const float* __restrict__ x,
                                             const float* __restrict__ gamma,
                                             u16* __restrict__ xn) {
  int row = blockIdx.x;
  int t = threadIdx.x;
  const float4* xr = (const float4*)(x + (size_t)row * DIMX);
  float4 v = xr[t];
  float ss = v.x * v.x + v.y * v.y + v.z * v.z + v.w * v.w;
#pragma unroll
  for (int o = 32; o > 0; o >>= 1) ss += __shfl_xor(ss, o, 64);
  __shared__ float wss[4];
  int w = t >> 6;
  if ((t & 63) == 0) wss[w] = ss;
  __syncthreads();
  float tot = wss[0] + wss[1] + wss[2] + wss[3];
  float scale = 32.0f / fmaxf(sqrtf(tot), 1e-12f);
  float4 g = ((const float4*)gamma)[t];
  ushort4 o4;
  o4.x = f2b(v.x * scale * g.x);
  o4.y = f2b(v.y * scale * g.y);
  o4.z = f2b(v.z * scale * g.z);
  o4.w = f2b(v.w * scale * g.w);
  ((ushort4*)xn)[(size_t)row * 256 + t] = o4;
}

// ---------------- transpose-cast ----------------
__global__ __launch_bounds__(256) void k_castT(const float* __restrict__ in,
                                               u16* __restrict__ out, int Rr, int Cc) {
  __shared__ float tile[32][33];
  int c0 = blockIdx.x * 32, r0 = blockIdx.y * 32;
  int tx = threadIdx.x, ty = threadIdx.y;
#pragma unroll
  for (int i = 0; i < 4; i++)
    tile[ty + i * 8][tx] = in[(size_t)(r0 + ty + i * 8) * Cc + c0 + tx];
  __syncthreads();
#pragma unroll
  for (int i = 0; i < 4; i++)
    out[(size_t)(c0 + ty + i * 8) * Rr + r0 + tx] = f2b(tile[tx][ty + i * 8]);
}

// ---------------- shared 128x128 GEMM core, BK=64, XOR bank-swizzled LDS -----
template<bool SWAP>
__device__ __forceinline__ void gemm_core128(const u16* __restrict__ Ag,
                                             const u16* __restrict__ Bg,
                                             u16* Al, u16* Bl,  // each [2*4096]
                                             int t, f32x4 (&acc)[4][4]) {
  int w = t >> 6, lane = t & 63;
  int r16 = lane & 15, q = lane >> 4;
  int wi = w >> 1, wj = w & 1;
  int swz = (r16 >> 1) & 3;
  int qs8 = ((q ^ swz) & 3) * 8;  // swizzled k-chunk offset for frag reads
  for (int k0 = 0; k0 < 1024; k0 += 64) {
    __syncthreads();
#pragma unroll
    for (int h = 0; h < 2; h++) {
#pragma unroll
      for (int r = 0; r < 2; r++) {
        int chunk = (r << 8) + t;
        int row = chunk >> 2;
        int cc = (chunk & 3) ^ ((row >> 1) & 3);  // inverse swizzle on source
        u16* la = Al + h * 4096 + ((r << 8) + (w << 6)) * 8;
        u16* lb = Bl + h * 4096 + ((r << 8) + (w << 6)) * 8;
        gl2lds16(Ag + (size_t)row * 1024 + k0 + h * 32 + cc * 8, la);
        gl2lds16(Bg + (size_t)row * 1024 + k0 + h * 32 + cc * 8, lb);
      }
    }
    __syncthreads();
#pragma unroll
    for (int h = 0; h < 2; h++) {
      bf16x8 af[4], bfr[4];
#pragma unroll
      for (int i = 0; i < 4; i++) {
        af[i]  = *(const bf16x8*)(Al + h * 4096 + (wi * 64 + i * 16 + r16) * 32 + qs8);
        bfr[i] = *(const bf16x8*)(Bl + h * 4096 + (wj * 64 + i * 16 + r16) * 32 + qs8);
      }
#pragma unroll
      for (int i = 0; i < 4; i++)
#pragma unroll
        for (int j = 0; j < 4; j++)
          acc[i][j] = SWAP
            ? __builtin_amdgcn_mfma_f32_16x16x32_bf16(bfr[j], af[i], acc[i][j], 0, 0, 0)
            : __builtin_amdgcn_mfma_f32_16x16x32_bf16(af[i], bfr[j], acc[i][j], 0, 0, 0);
    }
  }
}

// ---------------- GEMM1 merged q/k/v ----------------
__global__ __launch_bounds__(256) void k_gemm1(const u16* __restrict__ A,
                                               const u16* __restrict__ Bt,   // 3072x1024
                                               u16* __restrict__ qkT,        // 2048x16384
                                               u16* __restrict__ vmat,       // 16384x1024
                                               float* __restrict__ sumsq) {  // [4][2048]
  __shared__ u16 Al[2 * 4096];
  __shared__ u16 Bl[2 * 4096];
  int l = blockIdx.x;
  int xcd = l & 7, idx = l >> 3;
  int m0 = (xcd * 16 + (idx & 15)) * 128;
  int n0 = (idx >> 4) * 128;
  int t = threadIdx.x, lane = t & 63, w = t >> 6;
  int wi = w >> 1, wj = w & 1;
  int r16 = lane & 15, q = lane >> 4;
  f32x4 acc[4][4] = {};
  if (n0 < 2048) {
    gemm_core128<false>(A + (size_t)m0 * 1024, Bt + (size_t)n0 * 1024, Al, Bl, t, acc);
    int b = m0 >> 12;
#pragma unroll
    for (int j = 0; j < 4; j++) {
      int c = n0 + wj * 64 + j * 16 + r16;
      float colss = 0.f;
#pragma unroll
      for (int i = 0; i < 4; i++) {
        f32x4 a = acc[i][j];
        colss += a.x * a.x + a.y * a.y + a.z * a.z + a.w * a.w;
        int m = m0 + wi * 64 + i * 16 + q * 4;
        ushort4 o4;
        o4.x = f2b(a.x); o4.y = f2b(a.y); o4.z = f2b(a.z); o4.w = f2b(a.w);
        *(ushort4*)(qkT + (size_t)c * M_TOT + m) = o4;
      }
      colss += __shfl_xor(colss, 16, 64);
      colss += __shfl_xor(colss, 32, 64);
      if (lane < 16) atomicAdd(&sumsq[b * 2048 + c], colss);
    }
  } else {
    gemm_core128<true>(A + (size_t)m0 * 1024, Bt + (size_t)n0 * 1024, Al, Bl, t, acc);
    int vc0 = n0 - 2048;
#pragma unroll
    for (int i = 0; i < 4; i++) {
      int m = m0 + wi * 64 + i * 16 + r16;
#pragma unroll
      for (int j = 0; j < 4; j++) {
        int c = vc0 + wj * 64 + j * 16 + q * 4;
        f32x4 a = acc[i][j];
        ushort4 o4;
        o4.x = f2b(a.x); o4.y = f2b(a.y); o4.z = f2b(a.z); o4.w = f2b(a.w);
        *(ushort4*)(vmat + (size_t)m * 1024 + c) = o4;
      }
    }
  }
}

// ---------------- S partials: Spart[split][bh][d][e], wave-private bh, NO atomics ----
// grid (16, 16): g = bh-group, split; wave w handles bh = g*4+w over n-slice of 256.
// Swapped MFMA => acc reg-dim = e => f32x4 stores; full 64x64 tile per wave.
__global__ __launch_bounds__(256) void k_attn_s(const u16* __restrict__ qkT,
                                                float* __restrict__ Spart) {
  int g = blockIdx.x, split = blockIdx.y;
  int t = threadIdx.x, lane = t & 63, w = t >> 6;
  int bh = g * 4 + w;
  int b = bh >> 4, h = bh & 15;
  int r16 = lane & 15, q = lane >> 4;
  const u16* qbase = qkT + (size_t)(h * 64) * M_TOT + b * 4096;
  const u16* kbase = qkT + (size_t)(1024 + h * 64) * M_TOT + b * 4096;
  f32x4 acc[4][4] = {};
#pragma unroll
  for (int it = 0; it < 8; it++) {
    int kk = split * 256 + it * 32 + q * 8;
    bf16x8 af[4], bfr[4];
#pragma unroll
    for (int i = 0; i < 4; i++) af[i] = *(const bf16x8*)(qbase + (size_t)(i * 16 + r16) * M_TOT + kk);
#pragma unroll
    for (int j = 0; j < 4; j++) bfr[j] = *(const bf16x8*)(kbase + (size_t)(j * 16 + r16) * M_TOT + kk);
#pragma unroll
    for (int i = 0; i < 4; i++)
#pragma unroll
      for (int j = 0; j < 4; j++)
        acc[i][j] = __builtin_amdgcn_mfma_f32_16x16x32_bf16(bfr[j], af[i], acc[i][j], 0, 0, 0);
  }
  // acc[i][j]: d = i*16 + r16 (col), e = j*16 + q*4 + reg (row)
  float* Sp = Spart + ((size_t)split * 64 + bh) * 4096;
#pragma unroll
  for (int i = 0; i < 4; i++) {
    int d = i * 16 + r16;
#pragma unroll
    for (int j = 0; j < 4; j++) {
      int e = j * 16 + q * 4;
      *(f32x4*)(Sp + d * 64 + e) = acc[i][j];
    }
  }
}

// ---------------- sum 16 partials + scale + softmax -> PT[bh][e][d] bf16 ----------------
__global__ __launch_bounds__(64) void k_softmax(const float* __restrict__ Spart,
                                                const float* __restrict__ sumsq,
                                                const float* __restrict__ temp,
                                                u16* __restrict__ PT) {
  int bh = blockIdx.x;
  int b = bh >> 4, h = bh & 15;
  int d = threadIdx.x;
  __shared__ float rnk[64];
  rnk[d] = 1.0f / fmaxf(sqrtf(sumsq[b * 2048 + 1024 + h * 64 + d]), 1e-12f);
  __syncthreads();
  float nq = sqrtf(sumsq[b * 2048 + h * 64 + d]);
  float qs = 8.0f * __expf(temp[h]) / fmaxf(nq, 1e-12f);
  const float* Sp = Spart + (size_t)bh * 4096 + d * 64;
  float vals[64];
#pragma unroll
  for (int e = 0; e < 64; e += 4) {
    f32x4 v = {};
#pragma unroll
    for (int s = 0; s < 16; s++)
      v += *(const f32x4*)(Sp + (size_t)s * 64 * 4096 + e);
    vals[e + 0] = v.x; vals[e + 1] = v.y; vals[e + 2] = v.z; vals[e + 3] = v.w;
  }
  float mx = -3.0e38f;
#pragma unroll
  for (int e = 0; e < 64; e++) {
    float v = vals[e] * qs * rnk[e];
    vals[e] = v;
    mx = fmaxf(mx, v);
  }
  float sum = 0.f;
#pragma unroll
  for (int e = 0; e < 64; e++) {
    float v = __expf(vals[e] - mx);
    vals[e] = v;
    sum += v;
  }
  float inv = 1.0f / sum;
#pragma unroll
  for (int e = 0; e < 64; e++)
    PT[((size_t)bh * 64 + e) * 64 + d] = f2b(vals[e] * inv);
}

// ---------------- MT_b[o][h*64+e] = sum_d woT[o][h*64+d] * PT[e][d] ----------------
__global__ __launch_bounds__(256) void k_m(const u16* __restrict__ woT,
                                           const u16* __restrict__ PT,
                                           u16* __restrict__ MT) {
  int bh = blockIdx.x;
  int b = bh >> 4, h = bh & 15;
  int o0 = blockIdx.y * 128;
  int t = threadIdx.x, lane = t & 63, w = t >> 6;
  int r16 = lane & 15, q = lane >> 4;
  const u16* pbase = PT + (size_t)bh * 4096;
  f32x4 acc[2][4] = {};
#pragma unroll
  for (int ks = 0; ks < 2; ks++) {
    int kk = ks * 32 + q * 8;
    bf16x8 af[2], bfr[4];
#pragma unroll
    for (int i = 0; i < 2; i++)
      af[i] = *(const bf16x8*)(woT + (size_t)(o0 + w * 32 + i * 16 + r16) * 1024 + h * 64 + kk);
#pragma unroll
    for (int j = 0; j < 4; j++)
      bfr[j] = *(const bf16x8*)(pbase + (size_t)(j * 16 + r16) * 64 + kk);
#pragma unroll
    for (int i = 0; i < 2; i++)
#pragma unroll
      for (int j = 0; j < 4; j++)
        acc[i][j] = __builtin_amdgcn_mfma_f32_16x16x32_bf16(af[i], bfr[j], acc[i][j], 0, 0, 0);
  }
  u16* dst = MT + (size_t)b * 1024 * 1024;
#pragma unroll
  for (int i = 0; i < 2; i++) {
    int o = o0 + w * 32 + i * 16 + q * 4;
#pragma unroll
    for (int j = 0; j < 4; j++) {
      int e = h * 64 + j * 16 + r16;
      f32x4 a = acc[i][j];
      dst[(size_t)(o + 0) * 1024 + e] = f2b(a.x);
      dst[(size_t)(o + 1) * 1024 + e] = f2b(a.y);
      dst[(size_t)(o + 2) * 1024 + e] = f2b(a.z);
      dst[(size_t)(o + 3) * 1024 + e] = f2b(a.w);
    }
  }
}

// ---------------- GEMM2: out = vmat @ MT_b^T (fp32 out), swapped -> float4 stores ----
__global__ __launch_bounds__(256) void k_gemm2(const u16* __restrict__ A,
                                               const u16* __restrict__ Bt,
                                               float* __restrict__ C) {
  __shared__ u16 Al[2 * 4096];
  __shared__ u16 Bl[2 * 4096];
  int l = blockIdx.x;
  int xcd = l & 7, idx = l >> 3;
  int m0 = (xcd * 16 + (idx & 15)) * 128;
  int n0 = (idx >> 4) * 128;
  int b = m0 >> 12;
  const u16* Bb = Bt + (size_t)b * 1024 * 1024;
  int t = threadIdx.x, lane = t & 63, w = t >> 6;
  int wi = w >> 1, wj = w & 1;
  int r16 = lane & 15, q = lane >> 4;
  f32x4 acc[4][4] = {};
  gemm_core128<true>(A + (size_t)m0 * 1024, Bb + (size_t)n0 * 1024, Al, Bl, t, acc);
#pragma unroll
  for (int i = 0; i < 4; i++) {
    int m = m0 + wi * 64 + i * 16 + r16;
#pragma unroll
    for (int j = 0; j < 4; j++) {
      int c = n0 + wj * 64 + j * 16 + q * 4;
      *(f32x4*)(C + (size_t)m * 1024 + c) = acc[i][j];
    }
  }
}

extern "C" void kernel_launch(void* const* d_in, const int* in_sizes, int n_in,
                              void* d_out, int out_size, void* d_ws, size_t ws_size,
                              hipStream_t stream) {
  const float* x     = (const float*)d_in[0];
  const float* gamma = (const float*)d_in[1];
  const float* wqkv  = (const float*)d_in[2];
  const float* temp  = (const float*)d_in[3];
  const float* wout  = (const float*)d_in[4];
  float* out = (float*)d_out;

  char* ws = (char*)d_ws;
  size_t off = 0;
  u16* xn = (u16*)(ws + off);    off += (size_t)M_TOT * 1024 * 2;   // 32M (dead after gemm1)
  u16* wqT = (u16*)(ws + off);   off += (size_t)3072 * 1024 * 2;
  u16* woT = (u16*)(ws + off);   off += (size_t)1024 * 1024 * 2;
  u16* qkT = (u16*)(ws + off);   off += (size_t)2048 * M_TOT * 2;
  u16* vmat = (u16*)(ws + off);  off += (size_t)M_TOT * 1024 * 2;
  float* sumsq = (float*)(ws + off); off += (size_t)4 * 2048 * 4;
  u16* PT = (u16*)(ws + off);    off += (size_t)64 * 64 * 64 * 2;
  u16* MT = (u16*)(ws + off);    off += (size_t)4 * 1024 * 1024 * 2;

  // Spart[16][64][64][64] fp32 (16 MB) aliases xn (32 MB), which is dead after gemm1.
  float* Spart = (float*)xn;

  // only sumsq is atomic-accumulated
  hipMemsetAsync((void*)sumsq, 0, (size_t)4 * 2048 * 4, stream);

  k_rms<<<16384, 256, 0, stream>>>(x, gamma, xn);
  dim3 cb(32, 8);
  k_castT<<<dim3(3072 / 32, 1024 / 32), cb, 0, stream>>>(wqkv, wqT, 1024, 3072);
  k_castT<<<dim3(1024 / 32, 1024 / 32), cb, 0, stream>>>(wout, woT, 1024, 1024);
  k_gemm1<<<3072, 256, 0, stream>>>(xn, wqT, qkT, vmat, sumsq);
  k_attn_s<<<dim3(16, 16), 256, 0, stream>>>(qkT, Spart);
  k_softmax<<<64, 64, 0, stream>>>(Spart, sumsq, temp, PT);
  k_m<<<dim3(64, 8), 256, 0, stream>>>(woT, PT, MT);
  k_gemm2<<<1024, 256, 0, stream>>>(vmat, MT, out);
}